// Round 1
// baseline (1905.308 us; speedup 1.0000x reference)
//
#include <hip/hip_runtime.h>
#include <math.h>

// GCN encoder: h = GCNConv(vrepr, conv_w, conv_b, edges); loc = h@loc_w.T+loc_b;
// std = softplus(h@std_w.T+std_b)+1e-8; z = loc+std*eps; logvar = 2*log(std).
//
// d_out regions (each N*128 f32): R0 = z (scratch: h0, then std)
//                                 R1 = loc (scratch: h accumulator)
//                                 R2 = logvar (scratch: loc)
// d_ws: [0,N) dinv; [N, N+16384) conv_w transposed.  (needs ~466 KB)

#define GEMV_BLOCK 512
#define RPG 4
#define ROWS_PER_ITER 16

__global__ void k_deg_init(float* __restrict__ deg, int n) {
  int i = blockIdx.x * blockDim.x + threadIdx.x;
  if (i < n) deg[i] = 1.0f;  // self-loop
}

__global__ void k_deg_count(const int* __restrict__ dst, float* __restrict__ deg, int nE) {
  int i = blockIdx.x * blockDim.x + threadIdx.x;
  if (i < nE) atomicAdd(&deg[dst[i]], 1.0f);
}

__global__ void k_dinv(float* __restrict__ deg, int n) {
  int i = blockIdx.x * blockDim.x + threadIdx.x;
  if (i < n) deg[i] = rsqrtf(deg[i]);  // deg >= 1 always (self-loop)
}

// wt[j][k] = w[k][j]  (so GEMV reads contiguous rows of wt)
__global__ void k_transpose(const float* __restrict__ w, float* __restrict__ wt) {
  int t = blockIdx.x * blockDim.x + threadIdx.x;  // 16384 threads
  int j = t & 127, k = t >> 7;
  wt[j * 128 + k] = w[k * 128 + j];
}

// out[i][j] = sum_k x[i][k] * wt[j*128+k]  (+ per-mode epilogue)
// MODE 0: conv GEMM. aux = dinv[N].  out0 = h0, out1 = h0*dinv^2 (self-loop init)
// MODE 1: loc head.  aux = conv_b (added to x rows), bias = loc_b. out0 = loc
// MODE 2: std head.  aux = conv_b, bias = std_b. out0 = softplus(.)+1e-8
template <int MODE>
__global__ __launch_bounds__(GEMV_BLOCK)
void k_gemv(const float* __restrict__ x, const float* __restrict__ wt,
            const float* __restrict__ aux, const float* __restrict__ bias,
            float* __restrict__ out0, float* __restrict__ out1, int n)
{
  __shared__ float wl[128 * 128];              // 64 KB, XOR-swizzled float4 slots
  __shared__ float xs[ROWS_PER_ITER * 128];    // 8 KB staged input rows
  const int t = threadIdx.x;
  const int j = t & 127;     // output column
  const int g = t >> 7;      // row group 0..3

  const float4* w4 = (const float4*)wt;
  float4* wl4 = (float4*)wl;
#pragma unroll
  for (int m = t; m < 4096; m += GEMV_BLOCK) {
    int jj = m >> 5, kk = m & 31;
    wl4[jj * 32 + (kk ^ (jj & 7))] = w4[m];    // swizzle: 8 bank-quads per read
  }

  float4* xs4 = (float4*)xs;
  const float4* x4 = (const float4*)x;

  for (int base = blockIdx.x * ROWS_PER_ITER; base < n; base += gridDim.x * ROWS_PER_ITER) {
    __syncthreads();  // xs reuse from previous iteration
    {
      int r = t >> 5, k4 = t & 31;
      int row = base + r;
      float4 v = make_float4(0.f, 0.f, 0.f, 0.f);
      if (row < n) v = x4[(size_t)row * 32 + k4];
      if (MODE != 0) {
        float4 cb = ((const float4*)aux)[k4];  // + conv_b
        v.x += cb.x; v.y += cb.y; v.z += cb.z; v.w += cb.w;
      }
      xs4[t] = v;
    }
    __syncthreads();

    float acc[RPG] = {0.f, 0.f, 0.f, 0.f};
    const int r0 = g * RPG;
    const float4* wrow = wl4 + j * 32;
#pragma unroll 4
    for (int k4 = 0; k4 < 32; ++k4) {
      float4 wv = wrow[k4 ^ (j & 7)];
#pragma unroll
      for (int r = 0; r < RPG; ++r) {
        float4 xv = xs4[(r0 + r) * 32 + k4];   // broadcast (same addr across lanes)
        acc[r] = fmaf(wv.x, xv.x, fmaf(wv.y, xv.y, fmaf(wv.z, xv.z, fmaf(wv.w, xv.w, acc[r]))));
      }
    }

#pragma unroll
    for (int r = 0; r < RPG; ++r) {
      int row = base + r0 + r;
      if (row < n) {
        size_t o = (size_t)row * 128 + j;
        if (MODE == 0) {
          float di = aux[row];
          out0[o] = acc[r];
          out1[o] = acc[r] * di * di;          // self-loop contribution
        } else if (MODE == 1) {
          out0[o] = acc[r] + bias[j];
        } else {
          float v = acc[r] + bias[j];
          float sp = fmaxf(v, 0.f) + log1pf(expf(-fabsf(v)));  // stable softplus
          out0[o] = sp + 1e-8f;
        }
      }
    }
  }
}

__global__ __launch_bounds__(256)
void k_scatter(const int* __restrict__ src, const int* __restrict__ dst,
               const float* __restrict__ dinv, const float* __restrict__ h0,
               float* __restrict__ hacc, int nE)
{
  long long gt = (long long)blockIdx.x * 256 + threadIdx.x;
  int e = (int)(gt >> 7);
  int j = (int)(gt & 127);
  if (e >= nE) return;
  int s = src[e], d = dst[e];
  float norm = dinv[s] * dinv[d];
  float v = h0[(size_t)s * 128 + j] * norm;
  atomicAdd(&hacc[(size_t)d * 128 + j], v);
}

__global__ void k_final(const float4* __restrict__ eps, float4* __restrict__ r0,
                        float4* __restrict__ r1, float4* __restrict__ r2, int total4)
{
  int i = blockIdx.x * blockDim.x + threadIdx.x;
  if (i >= total4) return;
  float4 sd = r0[i];   // std (from MODE 2)
  float4 loc = r2[i];  // loc (from MODE 1)
  float4 e = eps[i];
  float4 z, lv;
  z.x = fmaf(sd.x, e.x, loc.x); z.y = fmaf(sd.y, e.y, loc.y);
  z.z = fmaf(sd.z, e.z, loc.z); z.w = fmaf(sd.w, e.w, loc.w);
  lv.x = 2.f * logf(sd.x); lv.y = 2.f * logf(sd.y);
  lv.z = 2.f * logf(sd.z); lv.w = 2.f * logf(sd.w);
  r0[i] = z;   // z
  r1[i] = loc; // loc (overwrites h accumulator)
  r2[i] = lv;  // logvar
}

extern "C" void kernel_launch(void* const* d_in, const int* in_sizes, int n_in,
                              void* d_out, int out_size, void* d_ws, size_t ws_size,
                              hipStream_t stream)
{
  const int*   edge   = (const int*)d_in[0];
  const float* eps    = (const float*)d_in[1];
  const float* vrepr  = (const float*)d_in[2];
  const float* conv_w = (const float*)d_in[3];
  const float* conv_b = (const float*)d_in[4];
  const float* loc_w  = (const float*)d_in[5];
  const float* loc_b  = (const float*)d_in[6];
  const float* std_w  = (const float*)d_in[7];
  const float* std_b  = (const float*)d_in[8];

  const int nE = in_sizes[0] / 2;
  const int n  = in_sizes[1] / 128;
  const size_t ND = (size_t)n * 128;

  float* dinv = (float*)d_ws;        // [n]
  float* wt   = dinv + n;            // [128*128] conv_w^T

  float* r0 = (float*)d_out;         // h0 -> std -> z
  float* r1 = r0 + ND;               // h accum -> loc
  float* r2 = r1 + ND;               // loc tmp -> logvar

  const int* srcIdx = edge;
  const int* dstIdx = edge + nE;

  k_deg_init<<<(n + 255) / 256, 256, 0, stream>>>(dinv, n);
  k_deg_count<<<(nE + 255) / 256, 256, 0, stream>>>(dstIdx, dinv, nE);
  k_dinv<<<(n + 255) / 256, 256, 0, stream>>>(dinv, n);
  k_transpose<<<64, 256, 0, stream>>>(conv_w, wt);

  // h0 = vrepr @ conv_w ; hacc = h0 * dinv^2 (self-loop)
  k_gemv<0><<<1024, GEMV_BLOCK, 0, stream>>>(vrepr, wt, dinv, nullptr, r0, r1, n);

  // hacc[dst] += h0[src] * dinv[src]*dinv[dst]
  {
    long long total = (long long)nE * 128;
    int grid = (int)((total + 255) / 256);
    k_scatter<<<grid, 256, 0, stream>>>(srcIdx, dstIdx, dinv, r0, r1, nE);
  }

  // loc_w / std_w are already [j][k] row-major (h @ W.T)
  k_gemv<1><<<1024, GEMV_BLOCK, 0, stream>>>(r1, loc_w, conv_b, loc_b, r2, nullptr, n);
  k_gemv<2><<<1024, GEMV_BLOCK, 0, stream>>>(r1, std_w, conv_b, std_b, r0, nullptr, n);

  k_final<<<(int)((ND / 4 + 255) / 256), 256, 0, stream>>>(
      (const float4*)eps, (float4*)r0, (float4*)r1, (float4*)r2, (int)(ND / 4));
}

// Round 2
// 909.554 us; speedup vs baseline: 2.0948x; 2.0948x over previous
//
#include <hip/hip_runtime.h>
#include <math.h>

// GCN encoder: h = GCNConv(vrepr, conv_w, conv_b, edges); loc = h@loc_w.T+loc_b;
// std = softplus(h@std_w.T+std_b)+1e-8; z = loc+std*eps; logvar = 2*log(std).
//
// Aggregation is GATHER-based: CSR bucketing by dst, then one block per dst
// row accumulates h0[src]*dinv[src] (scatter-atomics were 1.6 GB of HBM
// writes; gather writes each row once and the h0 gathers are L3-resident).
//
// d_out regions (each N*128 f32):
//   R0 = h0 -> std -> z
//   R1 = h (gather output) -> loc input
//   R2 = CSR scratch (srcSorted/cnt/rowOff/cursor/partials) -> loc -> logvar
// d_ws: [0,N) dinv; [N, N+16384) conv_w transposed.  (~466 KB, proven fit)

#define GEMV_BLOCK 512
#define RPG 4
#define ROWS_PER_ITER 16

// ---------------- degree / dinv ----------------

__global__ void k_zero_int(int* __restrict__ p, int n) {
  int i = blockIdx.x * blockDim.x + threadIdx.x;
  if (i < n) p[i] = 0;
}

__global__ void k_count(const int* __restrict__ dst, int* __restrict__ cnt, int nE) {
  int i = blockIdx.x * blockDim.x + threadIdx.x;
  if (i < nE) atomicAdd(&cnt[dst[i]], 1);
}

__global__ void k_dinv(const int* __restrict__ cnt, float* __restrict__ dinv, int n) {
  int i = blockIdx.x * blockDim.x + threadIdx.x;
  if (i < n) dinv[i] = rsqrtf((float)cnt[i] + 1.0f);  // +1 self-loop
}

// wt[j][k] = w[k][j]
__global__ void k_transpose(const float* __restrict__ w, float* __restrict__ wt) {
  int t = blockIdx.x * blockDim.x + threadIdx.x;  // 16384 threads
  int j = t & 127, k = t >> 7;
  wt[j * 128 + k] = w[k * 128 + j];
}

// ---------------- exclusive scan (3-kernel, 1024 items/block) ----------------

__global__ __launch_bounds__(256)
void k_scan1(const int* __restrict__ in, int* __restrict__ out,
             int* __restrict__ partials, int n)
{
  __shared__ int s[256];
  const int tid = threadIdx.x;
  int base = blockIdx.x * 1024 + tid * 4;
  int v[4];
#pragma unroll
  for (int u = 0; u < 4; ++u) v[u] = (base + u < n) ? in[base + u] : 0;
  int tsum = v[0] + v[1] + v[2] + v[3];
  s[tid] = tsum;
  __syncthreads();
  for (int off = 1; off < 256; off <<= 1) {
    int add = (tid >= off) ? s[tid - off] : 0;
    __syncthreads();
    s[tid] += add;
    __syncthreads();
  }
  int excl = s[tid] - tsum;
#pragma unroll
  for (int u = 0; u < 4; ++u) {
    if (base + u < n) out[base + u] = excl;
    excl += v[u];
  }
  if (tid == 255) partials[blockIdx.x] = s[255];
}

__global__ __launch_bounds__(256)
void k_scan2(int* __restrict__ partials, int nb)  // nb <= 1024
{
  __shared__ int s[256];
  const int tid = threadIdx.x;
  int base = tid * 4;
  int v[4];
#pragma unroll
  for (int u = 0; u < 4; ++u) v[u] = (base + u < nb) ? partials[base + u] : 0;
  int tsum = v[0] + v[1] + v[2] + v[3];
  s[tid] = tsum;
  __syncthreads();
  for (int off = 1; off < 256; off <<= 1) {
    int add = (tid >= off) ? s[tid - off] : 0;
    __syncthreads();
    s[tid] += add;
    __syncthreads();
  }
  int excl = s[tid] - tsum;
#pragma unroll
  for (int u = 0; u < 4; ++u) {
    if (base + u < nb) partials[base + u] = excl;
    excl += v[u];
  }
}

__global__ void k_scan3(int* __restrict__ out, const int* __restrict__ partials, int n) {
  int i = blockIdx.x * 256 + threadIdx.x;
  if (i < n) out[i] += partials[i >> 10];
}

// ---------------- bucket edges by dst ----------------

__global__ void k_bucket(const int* __restrict__ src, const int* __restrict__ dst,
                         const int* __restrict__ rowOff, int* __restrict__ cursor,
                         int* __restrict__ srcSorted, int nE)
{
  int e = blockIdx.x * 256 + threadIdx.x;
  if (e >= nE) return;
  int d = dst[e];
  int pos = atomicAdd(&cursor[d], 1);
  srcSorted[rowOff[d] + pos] = src[e];
}

// ---------------- gather aggregation: one block (128 thr) per dst ----------------

__global__ __launch_bounds__(128)
void k_gather(const int* __restrict__ srcSorted, const int* __restrict__ rowOff,
              const int* __restrict__ cnt, const float* __restrict__ dinv,
              const float* __restrict__ h0, float* __restrict__ out, int n)
{
  int d = blockIdx.x;
  if (d >= n) return;
  const int j = threadIdx.x;
  __shared__ int sidx[128];
  __shared__ float sdiv[128];
  const int off = rowOff[d];
  const int m = cnt[d];
  const float dd = dinv[d];
  float acc = h0[(size_t)d * 128 + j] * dd;  // self-loop: h0[d]*dinv[d]

  for (int c = 0; c < m; c += 128) {
    int lim = min(128, m - c);
    __syncthreads();
    if (j < lim) {
      int s = srcSorted[off + c + j];
      sidx[j] = s;
      sdiv[j] = dinv[s];
    }
    __syncthreads();
    int u = 0;
    for (; u + 4 <= lim; u += 4) {
      float a0 = h0[(size_t)sidx[u    ] * 128 + j];
      float a1 = h0[(size_t)sidx[u + 1] * 128 + j];
      float a2 = h0[(size_t)sidx[u + 2] * 128 + j];
      float a3 = h0[(size_t)sidx[u + 3] * 128 + j];
      acc = fmaf(a0, sdiv[u    ], acc);
      acc = fmaf(a1, sdiv[u + 1], acc);
      acc = fmaf(a2, sdiv[u + 2], acc);
      acc = fmaf(a3, sdiv[u + 3], acc);
    }
    for (; u < lim; ++u)
      acc = fmaf(h0[(size_t)sidx[u] * 128 + j], sdiv[u], acc);
  }
  out[(size_t)d * 128 + j] = acc * dd;
}

// ---------------- dense GEMV (128x128 weights in LDS) ----------------
// MODE 0: h0 = x @ wt^T            (wt = conv_w transposed)
// MODE 1: loc = (x+conv_b) @ W.T + bias
// MODE 2: std = softplus((x+conv_b) @ W.T + bias) + 1e-8
template <int MODE>
__global__ __launch_bounds__(GEMV_BLOCK)
void k_gemv(const float* __restrict__ x, const float* __restrict__ wt,
            const float* __restrict__ aux, const float* __restrict__ bias,
            float* __restrict__ out0, int n)
{
  __shared__ float wl[128 * 128];              // 64 KB, XOR-swizzled float4 slots
  __shared__ float xs[ROWS_PER_ITER * 128];    // 8 KB staged input rows
  const int t = threadIdx.x;
  const int j = t & 127;     // output column
  const int g = t >> 7;      // row group 0..3

  const float4* w4 = (const float4*)wt;
  float4* wl4 = (float4*)wl;
#pragma unroll
  for (int m = t; m < 4096; m += GEMV_BLOCK) {
    int jj = m >> 5, kk = m & 31;
    wl4[jj * 32 + (kk ^ (jj & 7))] = w4[m];
  }

  float4* xs4 = (float4*)xs;
  const float4* x4 = (const float4*)x;

  for (int base = blockIdx.x * ROWS_PER_ITER; base < n; base += gridDim.x * ROWS_PER_ITER) {
    __syncthreads();
    {
      int k4 = t & 31;
      int row = base + (t >> 5);
      float4 v = make_float4(0.f, 0.f, 0.f, 0.f);
      if (row < n) v = x4[(size_t)row * 32 + k4];
      if (MODE != 0) {
        float4 cb = ((const float4*)aux)[k4];
        v.x += cb.x; v.y += cb.y; v.z += cb.z; v.w += cb.w;
      }
      xs4[t] = v;
    }
    __syncthreads();

    float acc[RPG] = {0.f, 0.f, 0.f, 0.f};
    const int r0 = g * RPG;
    const float4* wrow = wl4 + j * 32;
#pragma unroll 4
    for (int k4 = 0; k4 < 32; ++k4) {
      float4 wv = wrow[k4 ^ (j & 7)];
#pragma unroll
      for (int r = 0; r < RPG; ++r) {
        float4 xv = xs4[(r0 + r) * 32 + k4];
        acc[r] = fmaf(wv.x, xv.x, fmaf(wv.y, xv.y, fmaf(wv.z, xv.z, fmaf(wv.w, xv.w, acc[r]))));
      }
    }

#pragma unroll
    for (int r = 0; r < RPG; ++r) {
      int row = base + r0 + r;
      if (row < n) {
        size_t o = (size_t)row * 128 + j;
        if (MODE == 0) {
          out0[o] = acc[r];
        } else if (MODE == 1) {
          out0[o] = acc[r] + bias[j];
        } else {
          float v = acc[r] + bias[j];
          float sp = fmaxf(v, 0.f) + log1pf(expf(-fabsf(v)));
          out0[o] = sp + 1e-8f;
        }
      }
    }
  }
}

// ---------------- final: z / loc / logvar ----------------

__global__ void k_final(const float4* __restrict__ eps, float4* __restrict__ r0,
                        float4* __restrict__ r1, float4* __restrict__ r2, int total4)
{
  int i = blockIdx.x * blockDim.x + threadIdx.x;
  if (i >= total4) return;
  float4 sd = r0[i];   // std (from MODE 2)
  float4 loc = r2[i];  // loc (from MODE 1)
  float4 e = eps[i];
  float4 z, lv;
  z.x = fmaf(sd.x, e.x, loc.x); z.y = fmaf(sd.y, e.y, loc.y);
  z.z = fmaf(sd.z, e.z, loc.z); z.w = fmaf(sd.w, e.w, loc.w);
  lv.x = 2.f * logf(sd.x); lv.y = 2.f * logf(sd.y);
  lv.z = 2.f * logf(sd.z); lv.w = 2.f * logf(sd.w);
  r0[i] = z;
  r1[i] = loc;
  r2[i] = lv;
}

extern "C" void kernel_launch(void* const* d_in, const int* in_sizes, int n_in,
                              void* d_out, int out_size, void* d_ws, size_t ws_size,
                              hipStream_t stream)
{
  const int*   edge   = (const int*)d_in[0];
  const float* eps    = (const float*)d_in[1];
  const float* vrepr  = (const float*)d_in[2];
  const float* conv_w = (const float*)d_in[3];
  const float* conv_b = (const float*)d_in[4];
  const float* loc_w  = (const float*)d_in[5];
  const float* loc_b  = (const float*)d_in[6];
  const float* std_w  = (const float*)d_in[7];
  const float* std_b  = (const float*)d_in[8];

  const int nE = in_sizes[0] / 2;
  const int n  = in_sizes[1] / 128;
  const size_t ND = (size_t)n * 128;

  float* dinv = (float*)d_ws;        // [n]
  float* wt   = dinv + n;            // [128*128]

  float* r0 = (float*)d_out;         // h0 -> std -> z
  float* r1 = r0 + ND;               // h -> loc input
  float* r2 = r1 + ND;               // CSR scratch -> loc -> logvar

  // CSR scratch lives in r2 (free until k_gemv<1> writes loc there)
  int* r2i       = (int*)r2;
  int* srcSorted = r2i;              // [nE]
  int* cnt       = srcSorted + nE;   // [n]
  int* rowOff    = cnt + n;          // [n]
  int* cursor    = rowOff + n;       // [n]
  int* partials  = cursor + n;       // [nb]

  const int* srcIdx = edge;
  const int* dstIdx = edge + nE;

  const int nb = (n + 1023) / 1024;  // scan blocks (98 for n=100k, <=1024 req'd)

  // zero cnt..cursor (3n ints; rowOff overwritten by scan anyway)
  k_zero_int<<<(3 * n + 255) / 256, 256, 0, stream>>>(cnt, 3 * n);
  k_count<<<(nE + 255) / 256, 256, 0, stream>>>(dstIdx, cnt, nE);
  k_dinv<<<(n + 255) / 256, 256, 0, stream>>>(cnt, dinv, n);
  k_transpose<<<64, 256, 0, stream>>>(conv_w, wt);

  // exclusive scan: cnt -> rowOff
  k_scan1<<<nb, 256, 0, stream>>>(cnt, rowOff, partials, n);
  k_scan2<<<1, 256, 0, stream>>>(partials, nb);
  k_scan3<<<(n + 255) / 256, 256, 0, stream>>>(rowOff, partials, n);

  // h0 = vrepr @ conv_w
  k_gemv<0><<<1024, GEMV_BLOCK, 0, stream>>>(vrepr, wt, nullptr, nullptr, r0, n);

  // bucket edges by dst, then gather-aggregate
  k_bucket<<<(nE + 255) / 256, 256, 0, stream>>>(srcIdx, dstIdx, rowOff, cursor, srcSorted, nE);
  k_gather<<<n, 128, 0, stream>>>(srcSorted, rowOff, cnt, dinv, r0, r1, n);

  // heads (W already [j][k] row-major for h @ W.T)
  k_gemv<1><<<1024, GEMV_BLOCK, 0, stream>>>(r1, loc_w, conv_b, loc_b, r2, n);
  k_gemv<2><<<1024, GEMV_BLOCK, 0, stream>>>(r1, std_w, conv_b, std_b, r0, n);

  k_final<<<(int)((ND / 4 + 255) / 256), 256, 0, stream>>>(
      (const float4*)eps, (float4*)r0, (float4*)r1, (float4*)r2, (int)(ND / 4));
}

// Round 3
// 743.347 us; speedup vs baseline: 2.5631x; 1.2236x over previous
//
#include <hip/hip_runtime.h>
#include <hip/hip_bf16.h>
#include <math.h>

// GCN encoder: h = GCNConv(vrepr, conv_w, conv_b, edges); loc = h@loc_w.T+loc_b;
// std = softplus(h@std_w.T+std_b)+1e-8; z = loc+std*eps; logvar = 2*log(std).
//
// Pipeline:
//   h0s = (vrepr @ conv_w) * dinv[row]   stored BF16 (halves gather traffic)
//   CSR bucket by dst -> gather: h[d] = dinv[d] * (h0s[d] + sum h0s[src])
//   fused heads: one pass over h computes z, loc, logvar (both weight
//   matrices resident in LDS; removes k_final's 300MB R/W)
//
// d_out regions (each N*128 f32):
//   R0 = h0s (bf16 scratch) -> z
//   R1 = h (gather out)     -> loc   (same-row overwrite inside k_heads)
//   R2 = CSR scratch        -> logvar
// d_ws: [0,N) dinv; [N, N+16384) conv_w transposed. (~466 KB)

#define GEMV_BLOCK 512
#define RPG 4
#define ROWS_PER_ITER 16

#define HEADS_BLOCK 512
#define HR 8
#define HROWS 32

// ---------------- degree / dinv / transpose ----------------

__global__ void k_zero_int(int* __restrict__ p, int n) {
  int i = blockIdx.x * blockDim.x + threadIdx.x;
  if (i < n) p[i] = 0;
}

__global__ void k_count(const int* __restrict__ dst, int* __restrict__ cnt, int nE) {
  int i = blockIdx.x * blockDim.x + threadIdx.x;
  if (i < nE) atomicAdd(&cnt[dst[i]], 1);
}

__global__ void k_dinv(const int* __restrict__ cnt, float* __restrict__ dinv, int n) {
  int i = blockIdx.x * blockDim.x + threadIdx.x;
  if (i < n) dinv[i] = rsqrtf((float)cnt[i] + 1.0f);  // +1 self-loop
}

__global__ void k_transpose(const float* __restrict__ w, float* __restrict__ wt) {
  int t = blockIdx.x * blockDim.x + threadIdx.x;  // 16384 threads
  int j = t & 127, k = t >> 7;
  wt[j * 128 + k] = w[k * 128 + j];
}

// ---------------- exclusive scan ----------------

__global__ __launch_bounds__(256)
void k_scan1(const int* __restrict__ in, int* __restrict__ out,
             int* __restrict__ partials, int n)
{
  __shared__ int s[256];
  const int tid = threadIdx.x;
  int base = blockIdx.x * 1024 + tid * 4;
  int v[4];
#pragma unroll
  for (int u = 0; u < 4; ++u) v[u] = (base + u < n) ? in[base + u] : 0;
  int tsum = v[0] + v[1] + v[2] + v[3];
  s[tid] = tsum;
  __syncthreads();
  for (int off = 1; off < 256; off <<= 1) {
    int add = (tid >= off) ? s[tid - off] : 0;
    __syncthreads();
    s[tid] += add;
    __syncthreads();
  }
  int excl = s[tid] - tsum;
#pragma unroll
  for (int u = 0; u < 4; ++u) {
    if (base + u < n) out[base + u] = excl;
    excl += v[u];
  }
  if (tid == 255) partials[blockIdx.x] = s[255];
}

__global__ __launch_bounds__(256)
void k_scan2(int* __restrict__ partials, int nb)
{
  __shared__ int s[256];
  const int tid = threadIdx.x;
  int base = tid * 4;
  int v[4];
#pragma unroll
  for (int u = 0; u < 4; ++u) v[u] = (base + u < nb) ? partials[base + u] : 0;
  int tsum = v[0] + v[1] + v[2] + v[3];
  s[tid] = tsum;
  __syncthreads();
  for (int off = 1; off < 256; off <<= 1) {
    int add = (tid >= off) ? s[tid - off] : 0;
    __syncthreads();
    s[tid] += add;
    __syncthreads();
  }
  int excl = s[tid] - tsum;
#pragma unroll
  for (int u = 0; u < 4; ++u) {
    if (base + u < nb) partials[base + u] = excl;
    excl += v[u];
  }
}

__global__ void k_scan3(int* __restrict__ out, const int* __restrict__ partials, int n) {
  int i = blockIdx.x * 256 + threadIdx.x;
  if (i < n) out[i] += partials[i >> 10];
}

// ---------------- bucket edges by dst ----------------

__global__ void k_bucket(const int* __restrict__ src, const int* __restrict__ dst,
                         const int* __restrict__ rowOff, int* __restrict__ cursor,
                         int* __restrict__ srcSorted, int nE)
{
  int e = blockIdx.x * 256 + threadIdx.x;
  if (e >= nE) return;
  int d = dst[e];
  int pos = atomicAdd(&cursor[d], 1);
  srcSorted[rowOff[d] + pos] = src[e];
}

// ---------------- conv GEMV: h0s = (vrepr @ conv_w) * dinv, bf16 ----------------

__global__ __launch_bounds__(GEMV_BLOCK)
void k_conv(const float* __restrict__ x, const float* __restrict__ wt,
            const float* __restrict__ dinv, __hip_bfloat16* __restrict__ out, int n)
{
  __shared__ float wl[128 * 128];
  __shared__ float xs[ROWS_PER_ITER * 128];
  const int t = threadIdx.x;
  const int j = t & 127;
  const int g = t >> 7;

  const float4* w4 = (const float4*)wt;
  float4* wl4 = (float4*)wl;
  for (int m = t; m < 4096; m += GEMV_BLOCK) {
    int jj = m >> 5, kk = m & 31;
    wl4[jj * 32 + (kk ^ (jj & 7))] = w4[m];
  }

  float4* xs4 = (float4*)xs;
  const float4* x4 = (const float4*)x;

  for (int base = blockIdx.x * ROWS_PER_ITER; base < n; base += gridDim.x * ROWS_PER_ITER) {
    __syncthreads();
    {
      int k4 = t & 31;
      int row = base + (t >> 5);
      float4 v = make_float4(0.f, 0.f, 0.f, 0.f);
      if (row < n) v = x4[(size_t)row * 32 + k4];
      xs4[t] = v;
    }
    __syncthreads();

    float acc[RPG] = {0.f, 0.f, 0.f, 0.f};
    const int r0 = g * RPG;
    const float4* wrow = wl4 + j * 32;
#pragma unroll 4
    for (int k4 = 0; k4 < 32; ++k4) {
      float4 wv = wrow[k4 ^ (j & 7)];
#pragma unroll
      for (int r = 0; r < RPG; ++r) {
        float4 xv = xs4[(r0 + r) * 32 + k4];
        acc[r] = fmaf(wv.x, xv.x, fmaf(wv.y, xv.y, fmaf(wv.z, xv.z, fmaf(wv.w, xv.w, acc[r]))));
      }
    }

#pragma unroll
    for (int r = 0; r < RPG; ++r) {
      int row = base + r0 + r;
      if (row < n)
        out[(size_t)row * 128 + j] = __float2bfloat16(acc[r] * dinv[row]);
    }
  }
}

// ---------------- gather: h[d] = dinv[d] * (h0s[d] + sum_src h0s[src]) ----------------

__global__ __launch_bounds__(128)
void k_gather(const int* __restrict__ srcSorted, const int* __restrict__ rowOff,
              const int* __restrict__ cnt, const float* __restrict__ dinv,
              const __hip_bfloat16* __restrict__ h0s, float* __restrict__ out, int n)
{
  int d = blockIdx.x;
  if (d >= n) return;
  const int j = threadIdx.x;
  __shared__ int sidx[128];
  const int off = rowOff[d];
  const int m = cnt[d];
  const float dd = dinv[d];
  float acc = __bfloat162float(h0s[(size_t)d * 128 + j]);  // self-loop (pre-scaled)

  for (int c = 0; c < m; c += 128) {
    int lim = min(128, m - c);
    __syncthreads();
    if (j < lim) sidx[j] = srcSorted[off + c + j];
    __syncthreads();
    int u = 0;
    for (; u + 8 <= lim; u += 8) {
      float s0 = __bfloat162float(h0s[(size_t)sidx[u    ] * 128 + j]);
      float s1 = __bfloat162float(h0s[(size_t)sidx[u + 1] * 128 + j]);
      float s2 = __bfloat162float(h0s[(size_t)sidx[u + 2] * 128 + j]);
      float s3 = __bfloat162float(h0s[(size_t)sidx[u + 3] * 128 + j]);
      float s4 = __bfloat162float(h0s[(size_t)sidx[u + 4] * 128 + j]);
      float s5 = __bfloat162float(h0s[(size_t)sidx[u + 5] * 128 + j]);
      float s6 = __bfloat162float(h0s[(size_t)sidx[u + 6] * 128 + j]);
      float s7 = __bfloat162float(h0s[(size_t)sidx[u + 7] * 128 + j]);
      acc += ((s0 + s1) + (s2 + s3)) + ((s4 + s5) + (s6 + s7));
    }
    for (; u < lim; ++u)
      acc += __bfloat162float(h0s[(size_t)sidx[u] * 128 + j]);
  }
  out[(size_t)d * 128 + j] = acc * dd;
}

// ---------------- fused heads: z / loc / logvar in one pass over h ----------------

__global__ __launch_bounds__(HEADS_BLOCK)
void k_heads(const float* __restrict__ h, const float* __restrict__ locW,
             const float* __restrict__ stdW, const float* __restrict__ convB,
             const float* __restrict__ locB, const float* __restrict__ stdB,
             const float* __restrict__ eps, float* __restrict__ zOut,
             float* __restrict__ locOut, float* __restrict__ lvOut, int n)
{
  __shared__ float wL[128 * 128];            // 64 KB
  __shared__ float wS[128 * 128];            // 64 KB
  __shared__ float xs[HROWS * 128];          // 16 KB  (total 144 KB <= 160)
  const int t = threadIdx.x;
  const int j = t & 127;
  const int g = t >> 7;                      // 0..3, HR=8 rows each

  float4* wL4 = (float4*)wL;
  float4* wS4 = (float4*)wS;
  for (int m = t; m < 4096; m += HEADS_BLOCK) {
    int jj = m >> 5, kk = m & 31;
    int slot = jj * 32 + (kk ^ (jj & 7));
    wL4[slot] = ((const float4*)locW)[m];
    wS4[slot] = ((const float4*)stdW)[m];
  }

  const float lb = locB[j];
  const float sb = stdB[j];
  const int sk4 = t & 31;
  float4 cb = ((const float4*)convB)[sk4];

  float4* xs4 = (float4*)xs;
  const float4* h4 = (const float4*)h;

  for (int base = blockIdx.x * HROWS; base < n; base += gridDim.x * HROWS) {
    __syncthreads();
    for (int m = t; m < HROWS * 32; m += HEADS_BLOCK) {  // m&31 == sk4
      int row = base + (m >> 5);
      float4 v = make_float4(0.f, 0.f, 0.f, 0.f);
      if (row < n) v = h4[(size_t)row * 32 + sk4];
      v.x += cb.x; v.y += cb.y; v.z += cb.z; v.w += cb.w;
      xs4[m] = v;
    }
    __syncthreads();

    float aL[HR], aS[HR];
#pragma unroll
    for (int r = 0; r < HR; ++r) { aL[r] = 0.f; aS[r] = 0.f; }
    const int r0 = g * HR;
    const float4* wrL = wL4 + j * 32;
    const float4* wrS = wS4 + j * 32;
#pragma unroll 4
    for (int k4 = 0; k4 < 32; ++k4) {
      int ks = k4 ^ (j & 7);
      float4 wl_ = wrL[ks];
      float4 ws_ = wrS[ks];
#pragma unroll
      for (int r = 0; r < HR; ++r) {
        float4 xv = xs4[(r0 + r) * 32 + k4];  // broadcast across wave
        aL[r] = fmaf(wl_.x, xv.x, fmaf(wl_.y, xv.y, fmaf(wl_.z, xv.z, fmaf(wl_.w, xv.w, aL[r]))));
        aS[r] = fmaf(ws_.x, xv.x, fmaf(ws_.y, xv.y, fmaf(ws_.z, xv.z, fmaf(ws_.w, xv.w, aS[r]))));
      }
    }

#pragma unroll
    for (int r = 0; r < HR; ++r) {
      int row = base + r0 + r;
      if (row < n) {
        size_t o = (size_t)row * 128 + j;
        float lc = aL[r] + lb;
        float sv0 = aS[r] + sb;
        float sv = fmaxf(sv0, 0.f) + log1pf(expf(-fabsf(sv0))) + 1e-8f;  // softplus+eps
        float e = eps[o];
        zOut[o] = fmaf(sv, e, lc);
        locOut[o] = lc;                 // overwrites h row (same block, after read)
        lvOut[o] = 2.f * logf(sv);
      }
    }
  }
}

extern "C" void kernel_launch(void* const* d_in, const int* in_sizes, int n_in,
                              void* d_out, int out_size, void* d_ws, size_t ws_size,
                              hipStream_t stream)
{
  const int*   edge   = (const int*)d_in[0];
  const float* eps    = (const float*)d_in[1];
  const float* vrepr  = (const float*)d_in[2];
  const float* conv_w = (const float*)d_in[3];
  const float* conv_b = (const float*)d_in[4];
  const float* loc_w  = (const float*)d_in[5];
  const float* loc_b  = (const float*)d_in[6];
  const float* std_w  = (const float*)d_in[7];
  const float* std_b  = (const float*)d_in[8];

  const int nE = in_sizes[0] / 2;
  const int n  = in_sizes[1] / 128;
  const size_t ND = (size_t)n * 128;

  float* dinv = (float*)d_ws;        // [n]
  float* wt   = dinv + n;            // [128*128] conv_w^T

  float* r0 = (float*)d_out;         // h0s (bf16) -> z
  float* r1 = r0 + ND;               // h -> loc
  float* r2 = r1 + ND;               // CSR scratch -> logvar

  __hip_bfloat16* h0s = (__hip_bfloat16*)r0;

  int* r2i       = (int*)r2;
  int* srcSorted = r2i;              // [nE]
  int* cnt       = srcSorted + nE;   // [n]
  int* rowOff    = cnt + n;          // [n]
  int* cursor    = rowOff + n;       // [n]
  int* partials  = cursor + n;       // [nb]

  const int* srcIdx = edge;
  const int* dstIdx = edge + nE;

  const int nb = (n + 1023) / 1024;

  k_zero_int<<<(3 * n + 255) / 256, 256, 0, stream>>>(cnt, 3 * n);
  k_count<<<(nE + 255) / 256, 256, 0, stream>>>(dstIdx, cnt, nE);
  k_dinv<<<(n + 255) / 256, 256, 0, stream>>>(cnt, dinv, n);
  k_transpose<<<64, 256, 0, stream>>>(conv_w, wt);

  k_scan1<<<nb, 256, 0, stream>>>(cnt, rowOff, partials, n);
  k_scan2<<<1, 256, 0, stream>>>(partials, nb);
  k_scan3<<<(n + 255) / 256, 256, 0, stream>>>(rowOff, partials, n);

  // h0s = (vrepr @ conv_w) * dinv  (bf16)
  k_conv<<<1024, GEMV_BLOCK, 0, stream>>>(vrepr, wt, dinv, h0s, n);

  k_bucket<<<(nE + 255) / 256, 256, 0, stream>>>(srcIdx, dstIdx, rowOff, cursor, srcSorted, nE);
  k_gather<<<n, 128, 0, stream>>>(srcSorted, rowOff, cnt, dinv, h0s, r1, n);

  // fused heads + reparameterization
  k_heads<<<1024, HEADS_BLOCK, 0, stream>>>(r1, loc_w, std_w, conv_b, loc_b, std_b,
                                            eps, r0, r1, r2, n);
}

// Round 4
// 696.584 us; speedup vs baseline: 2.7352x; 1.0671x over previous
//
#include <hip/hip_runtime.h>
#include <math.h>

// GCN encoder, restructured via linearity: h = Â(vrepr)@conv_w + conv_b,
// so aggregate vrepr FIRST, then one fused MFMA pass computes both heads
// with combined weights  WlT=(conv_w@loc_w.T).T, WsT=(conv_w@std_w.T).T,
// bl=conv_b@loc_w.T+loc_b, bs=conv_b@std_w.T+std_b:
//   loc = hagg@Wl+bl ; std = softplus(hagg@Ws+bs)+eps ; z=loc+std*eps ; lv=2ln(std)
//
// d_out regions (each N*128 f32):
//   R0 = vs (bf16 = vrepr*dinv) -> z
//   R1 = hagg (f32)             -> loc  (per-row self-overwrite in k_fused)
//   R2 = CSR scratch            -> logvar
// d_ws: dinv[n] f32 | WlT,WsT bf16[16384] | bl,bs f32[128]  (~467 KB)

typedef short short8 __attribute__((ext_vector_type(8)));
typedef float f32x4 __attribute__((ext_vector_type(4)));

static __device__ __forceinline__ unsigned short f2bf(float x) {
  unsigned u = __float_as_uint(x);
  unsigned r = (u + 0x7fffu + ((u >> 16) & 1u)) >> 16;   // round-nearest-even
  return (unsigned short)r;
}

// ---------------- degree / dinv ----------------

__global__ void k_zero_int(int* __restrict__ p, int n) {
  int i = blockIdx.x * blockDim.x + threadIdx.x;
  if (i < n) p[i] = 0;
}

__global__ void k_count(const int* __restrict__ dst, int* __restrict__ cnt, int nE) {
  int i = blockIdx.x * blockDim.x + threadIdx.x;
  if (i < nE) atomicAdd(&cnt[dst[i]], 1);
}

__global__ void k_dinv(const int* __restrict__ cnt, float* __restrict__ dinv, int n) {
  int i = blockIdx.x * blockDim.x + threadIdx.x;
  if (i < n) dinv[i] = rsqrtf((float)cnt[i] + 1.0f);  // +1 self-loop
}

// ---------------- exclusive scan ----------------

__global__ __launch_bounds__(256)
void k_scan1(const int* __restrict__ in, int* __restrict__ out,
             int* __restrict__ partials, int n)
{
  __shared__ int s[256];
  const int tid = threadIdx.x;
  int base = blockIdx.x * 1024 + tid * 4;
  int v[4];
#pragma unroll
  for (int u = 0; u < 4; ++u) v[u] = (base + u < n) ? in[base + u] : 0;
  int tsum = v[0] + v[1] + v[2] + v[3];
  s[tid] = tsum;
  __syncthreads();
  for (int off = 1; off < 256; off <<= 1) {
    int add = (tid >= off) ? s[tid - off] : 0;
    __syncthreads();
    s[tid] += add;
    __syncthreads();
  }
  int excl = s[tid] - tsum;
#pragma unroll
  for (int u = 0; u < 4; ++u) {
    if (base + u < n) out[base + u] = excl;
    excl += v[u];
  }
  if (tid == 255) partials[blockIdx.x] = s[255];
}

__global__ __launch_bounds__(256)
void k_scan2(int* __restrict__ partials, int nb)
{
  __shared__ int s[256];
  const int tid = threadIdx.x;
  int base = tid * 4;
  int v[4];
#pragma unroll
  for (int u = 0; u < 4; ++u) v[u] = (base + u < nb) ? partials[base + u] : 0;
  int tsum = v[0] + v[1] + v[2] + v[3];
  s[tid] = tsum;
  __syncthreads();
  for (int off = 1; off < 256; off <<= 1) {
    int add = (tid >= off) ? s[tid - off] : 0;
    __syncthreads();
    s[tid] += add;
    __syncthreads();
  }
  int excl = s[tid] - tsum;
#pragma unroll
  for (int u = 0; u < 4; ++u) {
    if (base + u < nb) partials[base + u] = excl;
    excl += v[u];
  }
}

// rowOff += partial ; cursor = rowOff (absolute-position bucketing)
__global__ void k_scan3(int* __restrict__ out, int* __restrict__ cursor,
                        const int* __restrict__ partials, int n) {
  int i = blockIdx.x * 256 + threadIdx.x;
  if (i < n) {
    int v = out[i] + partials[i >> 10];
    out[i] = v;
    cursor[i] = v;
  }
}

// ---------------- bucket edges by dst (cursor holds absolute pos) ----------------

__global__ void k_bucket(const int* __restrict__ src, const int* __restrict__ dst,
                         int* __restrict__ cursor, int* __restrict__ srcSorted, int nE)
{
  int e = blockIdx.x * 256 + threadIdx.x;
  if (e >= nE) return;
  int pos = atomicAdd(&cursor[dst[e]], 1);
  srcSorted[pos] = src[e];
}

// ---------------- vs = vrepr * dinv  (bf16x2 packed) ----------------

__global__ void k_vs(const float* __restrict__ vrepr, const float* __restrict__ dinv,
                     unsigned* __restrict__ vs, int n)
{
  int i = blockIdx.x * 256 + threadIdx.x;   // over n*64 bf16-pairs
  if (i >= n * 64) return;
  int row = i >> 6;
  float2 v = ((const float2*)vrepr)[i];
  float dd = dinv[row];
  unsigned lo = f2bf(v.x * dd);
  unsigned hi = f2bf(v.y * dd);
  vs[i] = lo | (hi << 16);
}

// ---------------- combined weights: wt[j][k] = sum_m cw[k][m]*hw[j][m] (bf16)
//                  bout[j] = sum_m cb[m]*hw[j][m] + hb[j] ----------------

__global__ __launch_bounds__(128)
void k_wcomb(const float* __restrict__ cw, const float* __restrict__ cb,
             const float* __restrict__ hw, const float* __restrict__ hb,
             unsigned short* __restrict__ wt, float* __restrict__ bout)
{
  int j = blockIdx.x, k = threadIdx.x;
  __shared__ float s[128];
  s[k] = hw[j * 128 + k];
  __syncthreads();
  float acc = 0.f;
  const float* r = cw + k * 128;
#pragma unroll 8
  for (int m = 0; m < 128; ++m) acc = fmaf(r[m], s[m], acc);
  wt[j * 128 + k] = f2bf(acc);
  if (k == 0) {
    float b = 0.f;
    for (int m = 0; m < 128; ++m) b = fmaf(cb[m], s[m], b);
    bout[j] = b + hb[j];
  }
}

// ---------------- gather: hagg[d] = dinv[d]*(vs[d] + sum_src vs[src]) ----------------
// 256 thr: wave = src-subslot u (0..3), lane = col-pair (full 256B row per wave-load)

__global__ __launch_bounds__(256)
void k_gather(const int* __restrict__ srcSorted, const int* __restrict__ rowOff,
              const int* __restrict__ cnt, const float* __restrict__ dinv,
              const unsigned* __restrict__ vs, float* __restrict__ hagg, int n)
{
  const int d = blockIdx.x;
  const int tid = threadIdx.x;
  const int u = tid >> 6;     // wave index = src sub-slot
  const int c = tid & 63;     // bf16-pair column
  __shared__ int sidx[128];
  __shared__ float red[4][128];

  const int off = rowOff[d];
  const int m = cnt[d];
  float ax = 0.f, ay = 0.f;
  if (u == 0) {  // self-loop (vs pre-scaled by dinv)
    unsigned p = vs[(size_t)d * 64 + c];
    ax = __uint_as_float(p << 16);
    ay = __uint_as_float(p & 0xffff0000u);
  }

  for (int cb = 0; cb < m; cb += 128) {
    int lim = min(128, m - cb);
    __syncthreads();
    if (tid < lim) sidx[tid] = srcSorted[off + cb + tid];
    __syncthreads();
    int sI = u;
    for (; sI + 12 < lim; sI += 16) {
      unsigned p0 = vs[(size_t)sidx[sI     ] * 64 + c];
      unsigned p1 = vs[(size_t)sidx[sI + 4 ] * 64 + c];
      unsigned p2 = vs[(size_t)sidx[sI + 8 ] * 64 + c];
      unsigned p3 = vs[(size_t)sidx[sI + 12] * 64 + c];
      ax += __uint_as_float(p0 << 16) + __uint_as_float(p1 << 16) +
            __uint_as_float(p2 << 16) + __uint_as_float(p3 << 16);
      ay += __uint_as_float(p0 & 0xffff0000u) + __uint_as_float(p1 & 0xffff0000u) +
            __uint_as_float(p2 & 0xffff0000u) + __uint_as_float(p3 & 0xffff0000u);
    }
    for (; sI < lim; sI += 4) {
      unsigned p = vs[(size_t)sidx[sI] * 64 + c];
      ax += __uint_as_float(p << 16);
      ay += __uint_as_float(p & 0xffff0000u);
    }
  }

  red[u][2 * c] = ax;
  red[u][2 * c + 1] = ay;
  __syncthreads();
  if (tid < 128) {
    float s = red[0][tid] + red[1][tid] + red[2][tid] + red[3][tid];
    hagg[(size_t)d * 128 + tid] = s * dinv[d];
  }
}

// ---------------- fused MFMA heads + reparameterization ----------------
// block = 512 thr (8 waves) = 32 rows. wave w: rows rg=(w>>2)*16, cols c0=(w&3)*32,
// BOTH heads. Weight frags resident in registers (16 x short8 = 64 VGPR).
// A: lane(L&15)=row, k0=8*(L>>4) [m92-verified pattern]; C/D: col=L&15, row=4*(L>>4)+reg.

__global__ __launch_bounds__(512)
void k_fused(const float* hagg,                         // == loc (aliased, no restrict)
             const unsigned short* __restrict__ wlT, const unsigned short* __restrict__ wsT,
             const float* __restrict__ bl, const float* __restrict__ bs,
             const float* __restrict__ eps,
             float* __restrict__ z, float* loc, float* __restrict__ lv, int n)
{
  const int t = threadIdx.x;
  const int w = t >> 6;
  const int L = t & 63;
  const int rg = (w >> 2) * 16;
  const int c0 = (w & 3) * 32;
  const int lr = L & 15;        // frag row (A) / col (B,C)
  const int lk = L >> 4;        // 0..3

  // resident B-frags [head][ct][kt]
  short8 bw[2][2][4];
  float blv[2], bsv[2];
#pragma unroll
  for (int head = 0; head < 2; ++head) {
    const unsigned short* W = head ? wsT : wlT;
#pragma unroll
    for (int ct = 0; ct < 2; ++ct) {
      int col = c0 + ct * 16 + lr;
#pragma unroll
      for (int kt = 0; kt < 4; ++kt)
        bw[head][ct][kt] = *(const short8*)(W + col * 128 + kt * 32 + lk * 8);
    }
  }
#pragma unroll
  for (int ct = 0; ct < 2; ++ct) {
    blv[ct] = bl[c0 + ct * 16 + lr];
    bsv[ct] = bs[c0 + ct * 16 + lr];
  }

  const int rbase = blockIdx.x * 32 + rg;
  const int arow = min(rbase + lr, n - 1);

  // A-frags: f32 -> bf16 in-register
  short8 a[4];
#pragma unroll
  for (int kt = 0; kt < 4; ++kt) {
    const float* p = hagg + (size_t)arow * 128 + kt * 32 + lk * 8;
    float4 f0 = *(const float4*)p;
    float4 f1 = *(const float4*)(p + 4);
    short8 v;
    v[0] = f2bf(f0.x); v[1] = f2bf(f0.y); v[2] = f2bf(f0.z); v[3] = f2bf(f0.w);
    v[4] = f2bf(f1.x); v[5] = f2bf(f1.y); v[6] = f2bf(f1.z); v[7] = f2bf(f1.w);
    a[kt] = v;
  }
  __syncthreads();   // all hagg reads of this block complete before loc stores

  f32x4 accL[2], accS[2];
#pragma unroll
  for (int ct = 0; ct < 2; ++ct) { accL[ct] = (f32x4)0.f; accS[ct] = (f32x4)0.f; }
#pragma unroll
  for (int kt = 0; kt < 4; ++kt) {
    accL[0] = __builtin_amdgcn_mfma_f32_16x16x32_bf16(a[kt], bw[0][0][kt], accL[0], 0, 0, 0);
    accL[1] = __builtin_amdgcn_mfma_f32_16x16x32_bf16(a[kt], bw[0][1][kt], accL[1], 0, 0, 0);
    accS[0] = __builtin_amdgcn_mfma_f32_16x16x32_bf16(a[kt], bw[1][0][kt], accS[0], 0, 0, 0);
    accS[1] = __builtin_amdgcn_mfma_f32_16x16x32_bf16(a[kt], bw[1][1][kt], accS[1], 0, 0, 0);
  }

#pragma unroll
  for (int ct = 0; ct < 2; ++ct) {
    int col = c0 + ct * 16 + lr;
#pragma unroll
    for (int reg = 0; reg < 4; ++reg) {
      int row = rbase + lk * 4 + reg;
      if (row < n) {
        size_t o = (size_t)row * 128 + col;
        float lc = accL[ct][reg] + blv[ct];
        float s0 = accS[ct][reg] + bsv[ct];
        float sv = fmaxf(s0, 0.f) + log1pf(expf(-fabsf(s0))) + 1e-8f;
        float e = eps[o];
        z[o] = fmaf(sv, e, lc);
        loc[o] = lc;
        lv[o] = 2.f * logf(sv);
      }
    }
  }
}

extern "C" void kernel_launch(void* const* d_in, const int* in_sizes, int n_in,
                              void* d_out, int out_size, void* d_ws, size_t ws_size,
                              hipStream_t stream)
{
  const int*   edge   = (const int*)d_in[0];
  const float* eps    = (const float*)d_in[1];
  const float* vrepr  = (const float*)d_in[2];
  const float* conv_w = (const float*)d_in[3];
  const float* conv_b = (const float*)d_in[4];
  const float* loc_w  = (const float*)d_in[5];
  const float* loc_b  = (const float*)d_in[6];
  const float* std_w  = (const float*)d_in[7];
  const float* std_b  = (const float*)d_in[8];

  const int nE = in_sizes[0] / 2;
  const int n  = in_sizes[1] / 128;
  const size_t ND = (size_t)n * 128;

  float*          dinv = (float*)d_ws;               // [n]
  unsigned short* wlT  = (unsigned short*)(dinv + n); // [16384] bf16
  unsigned short* wsT  = wlT + 16384;                 // [16384] bf16
  float*          bl   = (float*)(wsT + 16384);       // [128]
  float*          bs   = bl + 128;                    // [128]

  float* r0 = (float*)d_out;         // vs (bf16) -> z
  float* r1 = r0 + ND;               // hagg (f32) -> loc
  float* r2 = r1 + ND;               // CSR scratch -> logvar

  unsigned* vs = (unsigned*)r0;

  int* r2i       = (int*)r2;
  int* srcSorted = r2i;              // [nE]
  int* cnt       = srcSorted + nE;   // [n]
  int* rowOff    = cnt + n;          // [n]
  int* cursor    = rowOff + n;       // [n]
  int* partials  = cursor + n;       // [nb]

  const int* srcIdx = edge;
  const int* dstIdx = edge + nE;
  const int nb = (n + 1023) / 1024;

  k_zero_int<<<(n + 255) / 256, 256, 0, stream>>>(cnt, n);
  k_count<<<(nE + 255) / 256, 256, 0, stream>>>(dstIdx, cnt, nE);
  k_dinv<<<(n + 255) / 256, 256, 0, stream>>>(cnt, dinv, n);

  k_scan1<<<nb, 256, 0, stream>>>(cnt, rowOff, partials, n);
  k_scan2<<<1, 256, 0, stream>>>(partials, nb);
  k_scan3<<<(n + 255) / 256, 256, 0, stream>>>(rowOff, cursor, partials, n);

  k_vs<<<(n * 64 + 255) / 256, 256, 0, stream>>>(vrepr, dinv, vs, n);
  k_wcomb<<<128, 128, 0, stream>>>(conv_w, conv_b, loc_w, loc_b, wlT, bl);
  k_wcomb<<<128, 128, 0, stream>>>(conv_w, conv_b, std_w, std_b, wsT, bs);

  k_bucket<<<(nE + 255) / 256, 256, 0, stream>>>(srcIdx, dstIdx, cursor, srcSorted, nE);
  k_gather<<<n, 256, 0, stream>>>(srcSorted, rowOff, cnt, dinv, vs, r1, n);

  k_fused<<<(n + 31) / 32, 512, 0, stream>>>(r1, wlT, wsT, bl, bs, eps, r0, r1, r2, n);
}